// Round 12
// baseline (195.427 us; speedup 1.0000x reference)
//
#include <hip/hip_runtime.h>
#include <hip/hip_bf16.h>

// Problem constants
#define BB 16
#define CC 64
#define HH 64
#define WW 64
#define QQ 8192
#define HID 256
#define KK 576            // C*9
#define HT 66             // H + 2 halo
#define FROW 264          // 257 channels padded to 264 (16B-aligned rows)

typedef short short8 __attribute__((ext_vector_type(8)));
typedef short sv4    __attribute__((ext_vector_type(4)));
typedef float f32x4  __attribute__((ext_vector_type(4)));

__device__ __forceinline__ short f2bf(float f) {
    union { float f; unsigned u; } v; v.f = f;
    unsigned r = v.u + 0x7fffu + ((v.u >> 16) & 1u);
    return (short)(r >> 16);
}
__device__ __forceinline__ float bf2f(short s) {
    union { unsigned u; float f; } v; v.u = ((unsigned)(unsigned short)s) << 16;
    return v.f;
}
// Barrier that only drains LDS (lgkmcnt) — does NOT force vmcnt(0).
__device__ __forceinline__ void barrier_lds() {
    asm volatile("s_waitcnt lgkmcnt(0)" ::: "memory");
    __builtin_amdgcn_s_barrier();
    asm volatile("" ::: "memory");
}
// Async global->LDS DMA, 16B per lane (dest = wave-uniform base + lane*16).
__device__ __forceinline__ void glld16(const short* g, short* l) {
    __builtin_amdgcn_global_load_lds(
        (const __attribute__((address_space(1))) void*)g,
        (__attribute__((address_space(3))) void*)l, 16, 0, 0);
}

// ---------------------------------------------------------------------------
// Kernel T+P fused (R8 K-order): feat transpose + weight repack into
// per-K-step contiguous DMA blocks:
//   w3cB[kchunk*2176 + n*8 + j]: kglob = kchunk*8+j, pos = kglob>>6, c = kglob&63
//   w2cB[kchunk*2048 + n*8 + j] = w2[kchunk*8+j][n]
// ---------------------------------------------------------------------------
__global__ __launch_bounds__(256) void prep_transpose_k(const float* __restrict__ feat,
                                                        const float* __restrict__ w2,
                                                        const float* __restrict__ w3,
                                                        const float* __restrict__ b3,
                                                        short* __restrict__ featT,
                                                        short* __restrict__ w3cB,
                                                        short* __restrict__ w2cB) {
    __shared__ float ftile[64][65];
    const int t = threadIdx.x;
    const int gidx = blockIdx.x * 256 + t;   // grid = 1056 wgs

    if (gidx < 156672) {                      // 72 kchunks * 272 n * 8
        int kchunk = gidx / 2176;
        int rem = gidx - kchunk * 2176;
        int n = rem >> 3, j = rem & 7;
        int kglob = kchunk * 8 + j;
        int pos = kglob >> 6, c = kglob & 63;
        float v = 0.f;
        if (n < 256)      v = w3[n * KK + c * 9 + pos];
        else if (n == 256) v = b3[c * 9 + pos];
        w3cB[gidx] = f2bf(v);
    }
    if (gidx < 65536) {                       // 32 kchunks * 256 n * 8
        int kchunk = gidx >> 11;
        int rem = gidx & 2047;
        int n = rem >> 3, j = rem & 7;
        int k = kchunk * 8 + j;
        w2cB[gidx] = f2bf(w2[k * 256 + n]);
    }

    const int b = blockIdx.x / HT;
    const int yy = blockIdx.x - b * HT;
    short* out_row = featT + ((b * HT + yy) * HT) * 64;

    if (yy == 0 || yy == HT - 1) {
        for (int idx = t; idx < HT * 64; idx += 256) out_row[idx] = 0;
        return;
    }
    const int y = yy - 1;
    const float* src = feat + ((b * CC) * HH + y) * WW;
#pragma unroll
    for (int i = 0; i < 16; ++i) {
        int idx = i * 256 + t;
        int c = idx >> 6, x = idx & 63;
        ftile[c][x] = src[c * (HH * WW) + x];
    }
    if (t < 64) out_row[t] = 0;
    else if (t < 128) out_row[(HT - 1) * 64 + (t - 64)] = 0;
    __syncthreads();
#pragma unroll
    for (int i = 0; i < 16; ++i) {
        int idx = i * 256 + t;
        int x = idx >> 6, c = idx & 63;
        out_row[(x + 1) * 64 + c] = f2bf(ftile[c][x]);
    }
}

// ---------------------------------------------------------------------------
// Kernel C v7 (R10, verified no-spill): 512 threads, M=128 (y-pair).
// Grid = 512 wgs = exactly 2/CU -> ONE resident generation of 18 K-steps.
// Two output rows share one 4-row input slab; per-step B-tile DMA (17.4 KB)
// feeds 2x the MFMAs of the M=64 version.
// ---------------------------------------------------------------------------
#define SSTR 72   // slab row stride (shorts)
__global__ __launch_bounds__(512, 4) void conv_k(const short* __restrict__ featT,
                                                 const short* __restrict__ w3cB,
                                                 short* __restrict__ F) {
    __shared__ short slab[4 * HT * SSTR];   // 19,008 shorts = 38,016 B
    __shared__ short Bb[2][8704];           // 2 x 17,408 B
    const int t = threadIdx.x;
    const int wave = t >> 6, lane = t & 63, quad = lane >> 4, ln16 = lane & 15;
    const int mh = wave >> 2, nq = wave & 3;
    const int b = blockIdx.x >> 5;
    const int y0 = (blockIdx.x & 31) * 2;

    f32x4 acc[4][5];
#pragma unroll
    for (int a = 0; a < 4; ++a)
#pragma unroll
        for (int i = 0; i < 5; ++i) acc[a][i] = (f32x4){0.f, 0.f, 0.f, 0.f};

    auto stageB = [&](int buf, int st) {
        const short* src = w3cB + st * 8704;
#pragma unroll
        for (int u = 0; u < 2; ++u) {
            int cidx = u * 8 + wave;
            glld16(src + cidx * 512 + lane * 8, &Bb[buf][cidx * 512]);
        }
        if (wave == 0)
            glld16(src + 16 * 512 + lane * 8, &Bb[buf][16 * 512]);
    };

    stageB(0, 0);   // DMA in flight during slab staging

    const short* slabsrc = featT + b * (HT * HT * 64) + y0 * (HT * 64);
#pragma unroll
    for (int it = 0; it < 5; ++it) {
        int i = it * 512 + t;               // 2112 chunks of 8 shorts
        if (i < 2112) {
            short8 v = *(const short8*)(slabsrc + i * 8);
            *(short8*)(&slab[(i >> 3) * SSTR + (i & 7) * 8]) = v;
        }
    }
    __syncthreads();   // drains slab stores (lgkm) + B DMA (vmcnt)

#pragma unroll
    for (int st = 0; st < 18; ++st) {
        const int cur = st & 1;
        if (st < 17) stageB(cur ^ 1, st + 1);
        const int pos = st >> 1, ks = st & 1;
        const int di = pos / 3, dj = pos - di * 3;
        short8 af[4];
#pragma unroll
        for (int ms = 0; ms < 4; ++ms)
            af[ms] = *(const short8*)(&slab[((mh + di) * HT + ms * 16 + ln16 + dj) * SSTR + ks * 32 + quad * 8]);
#pragma unroll
        for (int i = 0; i < 5; ++i) {
            int sub = (i < 4) ? (nq + 4 * i) : 16;
            short8 bf = *(const short8*)(&Bb[cur][(quad * 272 + sub * 16 + ln16) * 8]);
#pragma unroll
            for (int ms = 0; ms < 4; ++ms)
                acc[ms][i] = __builtin_amdgcn_mfma_f32_16x16x32_bf16(af[ms], bf, acc[ms][i], 0, 0, 0);
        }
        __syncthreads();
    }

    // Epilogue: per output row (h = mh), scatter into 64xFROW LDS (reusing
    // slab), then full-line coalesced copy.
#pragma unroll
    for (int h = 0; h < 2; ++h) {
        if (mh == h) {
#pragma unroll
            for (int i = 0; i < 5; ++i) {
                int sub = (i < 4) ? (nq + 4 * i) : 16;
                int n = sub * 16 + ln16;
                bool store = (i < 4) || (nq == 0 && n < FROW);
                if (store) {
#pragma unroll
                    for (int ms = 0; ms < 4; ++ms)
#pragma unroll
                        for (int r = 0; r < 4; ++r) {
                            int xl = ms * 16 + quad * 4 + r;   // local x 0..63
                            slab[xl * FROW + n] = f2bf(acc[ms][i][r]);
                        }
                }
            }
        }
        __syncthreads();
        short8* dst = (short8*)(F + (long)((b * 64 + y0 + h) * 64) * FROW);
        const short8* src8 = (const short8*)slab;
#pragma unroll
        for (int it = 0; it < 5; ++it) {
            int idx = it * 512 + t;
            if (idx < (64 * FROW) / 8) dst[idx] = src8[idx];
        }
        __syncthreads();
    }
}

// ---------------------------------------------------------------------------
// Kernel M v10: 256 threads, TWO query tiles (128 queries) per wg.
//   Each DMA'd 16 KB w2 tile now feeds 32 MFMAs (2 tiles x 16) and grid
//   halves to 1024 -> 2 generations instead of 4. K-split Hh per tile
//   (2 x 64 x 136); v9 recompute trick (waves 2/3 recompute H1 at s==3) so
//   no persistent hv regs. acc2 = 128 AGPR + ~100 VGPR < 256 cap (256,2).
// ---------------------------------------------------------------------------
#define HSPLIT 136   // 272B rows, 16B-aligned
__global__ __launch_bounds__(256, 2) void mlp_k(const float* __restrict__ coord,
                                                const float* __restrict__ cell,
                                                const float* __restrict__ w1,
                                                const float* __restrict__ b1,
                                                const float* __restrict__ b2v,
                                                const short* __restrict__ w2cB,
                                                const short* __restrict__ F,
                                                float* __restrict__ out) {
    __shared__ short Hh[2 * 64 * HSPLIT];   // 34,816 B (half-K, 2 tiles)
    __shared__ short Wb[2][8192];           // 32,768 B
    __shared__ float red_s[128][4];         // 2,048 B
    __shared__ float fbv_s[128];            // 512 B

    const int t = threadIdx.x;
    const int wave = t >> 6, lane = t & 63, quad = lane >> 4, ln16 = lane & 15;
    const int qbase = blockIdx.x * 128;
    const int b = blockIdx.x >> 6;          // 64 wgs per batch

    auto stageW = [&](int buf, int s) {
        const short* src = w2cB + s * 8192;
#pragma unroll
        for (int u = 0; u < 4; ++u) {
            int cidx = u * 4 + wave;
            glld16(src + cidx * 512 + lane * 8, &Wb[buf][cidx * 512]);
        }
    };

    stageW(0, 0);   // DMA in flight through coord + H1 compute

    // --- coords for both tiles' own-lane queries ---
    int   lin[2];
    float in0[2], in1[2], in2[2];
#pragma unroll
    for (int T = 0; T < 2; ++T) {
        const int g = qbase + T * 64 + lane;
        const float2 cc = *(const float2*)(coord + g * 2);
        const float2 ce = *(const float2*)(cell + g * 2);
        const float coy = cc.x - ce.x * 0.5f, cox = cc.y - ce.y * 0.5f;
        const float cqy = fminf(fmaxf(coy + 1e-6f, -0.999999f), 0.999999f);
        const float cqx = fminf(fmaxf(cox + 1e-6f, -0.999999f), 0.999999f);
        int iy = (int)rintf(((cqy + 1.0f) * 64.0f - 1.0f) * 0.5f); iy = min(max(iy, 0), 63);
        int ix = (int)rintf(((cqx + 1.0f) * 64.0f - 1.0f) * 0.5f); ix = min(max(ix, 0), 63);
        lin[T] = iy * 64 + ix;
        in0[T] = (coy - ((float)iy * (1.0f / 32.0f) - 1.0f)) * 32.0f;
        in1[T] = (cox - ((float)ix * (1.0f / 32.0f) - 1.0f)) * 32.0f;
        in2[T] = ce.x * 32.0f;
    }

    // H1 for own query of tile T, k-slice [wave*64, +64) -> Hh col (wave&1)*64
    auto computeH1_write = [&](int T) {
        const int kbase = wave * 64;
        const int col = (wave & 1) * 64;
#pragma unroll
        for (int c8 = 0; c8 < 8; ++c8) {
            const int k0 = kbase + c8 * 8;
            f32x4 wa0 = *(const f32x4*)(w1 + k0),       wa1 = *(const f32x4*)(w1 + k0 + 4);
            f32x4 wb0 = *(const f32x4*)(w1 + 256 + k0), wb1 = *(const f32x4*)(w1 + 256 + k0 + 4);
            f32x4 wc0 = *(const f32x4*)(w1 + 512 + k0), wc1 = *(const f32x4*)(w1 + 512 + k0 + 4);
            f32x4 bb0 = *(const f32x4*)(b1 + k0),       bb1 = *(const f32x4*)(b1 + k0 + 4);
            short8 hv;
#pragma unroll
            for (int jj = 0; jj < 4; ++jj) {
                float v0 = fmaf(in0[T], wa0[jj], fmaf(in1[T], wb0[jj], fmaf(in2[T], wc0[jj], bb0[jj])));
                float v1 = fmaf(in0[T], wa1[jj], fmaf(in1[T], wb1[jj], fmaf(in2[T], wc1[jj], bb1[jj])));
                hv[jj]     = f2bf(fmaxf(v0, 0.f));
                hv[jj + 4] = f2bf(fmaxf(v1, 0.f));
            }
            *(short8*)(&Hh[(T * 64 + lane) * HSPLIT + col + c8 * 8]) = hv;
        }
    };

    if (wave < 2) { computeH1_write(0); computeH1_write(1); }   // phase-0: k<128
    f32x4 b2q[4];
#pragma unroll
    for (int i = 0; i < 4; ++i)
        b2q[i] = *(const f32x4*)(b2v + wave * 64 + i * 16 + quad * 4);
    __syncthreads();   // drains phase-0 H writes (lgkm) + Wb(0) DMA (vmcnt)

    // --- H2^T MFMA loop: 32 MFMAs per step (2 tiles x 4n x 4m) ---
    f32x4 acc2[2][4][4];
#pragma unroll
    for (int T = 0; T < 2; ++T)
#pragma unroll
        for (int i = 0; i < 4; ++i)
#pragma unroll
            for (int ms = 0; ms < 4; ++ms) acc2[T][i][ms] = (f32x4){0.f, 0.f, 0.f, 0.f};
#pragma unroll
    for (int s = 0; s < 8; ++s) {
        const int cur = s & 1;
        if (s < 7) stageW(cur ^ 1, s + 1);
        short8 wf[4];
#pragma unroll
        for (int i = 0; i < 4; ++i)
            wf[i] = *(const short8*)(&Wb[cur][(quad * 256 + wave * 64 + i * 16 + ln16) * 8]);
        const int col = (s & 3) * 32 + quad * 8;    // k within current half
#pragma unroll
        for (int T = 0; T < 2; ++T) {
            short8 hf[4];
#pragma unroll
            for (int ms = 0; ms < 4; ++ms)
                hf[ms] = *(const short8*)(&Hh[(T * 64 + ms * 16 + ln16) * HSPLIT + col]);
#pragma unroll
            for (int i = 0; i < 4; ++i)
#pragma unroll
                for (int ms = 0; ms < 4; ++ms)
                    acc2[T][i][ms] = __builtin_amdgcn_mfma_f32_16x16x32_bf16(wf[i], hf[ms], acc2[T][i][ms], 0, 0, 0);
        }
        if (s == 3) {
            __syncthreads();          // drain DMA(4); phase-0 H reads done
            if (wave >= 2) { computeH1_write(0); computeH1_write(1); }  // k>=128
            barrier_lds();            // phase-1 visible (lgkm only)
        } else if (s < 7) {
            __syncthreads();          // drain DMA(s+1)
        }
    }

    // --- per tile: F gather, combine, reduce ---
    const short* Fb = F + (long)b * 4096 * FROW;
#pragma unroll
    for (int T = 0; T < 2; ++T) {
        sv4 fv[4][4];
#pragma unroll
        for (int ms = 0; ms < 4; ++ms) {
            int linm = __shfl(lin[T], ms * 16 + ln16, 64);
            const short* Fr = Fb + (long)linm * FROW + wave * 64 + quad * 4;
#pragma unroll
            for (int i = 0; i < 4; ++i) fv[ms][i] = *(const sv4*)(Fr + i * 16);
        }
        float part[4] = {0.f, 0.f, 0.f, 0.f};
#pragma unroll
        for (int i = 0; i < 4; ++i)
#pragma unroll
            for (int ms = 0; ms < 4; ++ms)
#pragma unroll
                for (int r = 0; r < 4; ++r)
                    part[ms] = fmaf(fmaxf(acc2[T][i][ms][r] + b2q[i][r], 0.f), bf2f(fv[ms][i][r]), part[ms]);
#pragma unroll
        for (int ms = 0; ms < 4; ++ms) {
            part[ms] += __shfl_xor(part[ms], 16, 64);
            part[ms] += __shfl_xor(part[ms], 32, 64);
        }
        if (quad == 0) {
#pragma unroll
            for (int ms = 0; ms < 4; ++ms) red_s[T * 64 + ms * 16 + ln16][wave] = part[ms];
        }
        if (wave == T)
            fbv_s[T * 64 + lane] = bf2f(Fb[(long)lin[T] * FROW + 256]);
    }
    barrier_lds();
    if (t < 128)
        out[qbase + t] = red_s[t][0] + red_s[t][1] + red_s[t][2] + red_s[t][3] + fbv_s[t];
}

// ---------------------------------------------------------------------------
extern "C" void kernel_launch(void* const* d_in, const int* in_sizes, int n_in,
                              void* d_out, int out_size, void* d_ws, size_t ws_size,
                              hipStream_t stream) {
    const float* feat  = (const float*)d_in[0];
    const float* coord = (const float*)d_in[1];
    const float* cell  = (const float*)d_in[2];
    const float* w1    = (const float*)d_in[3];
    const float* b1    = (const float*)d_in[4];
    const float* w2    = (const float*)d_in[5];
    const float* b2    = (const float*)d_in[6];
    const float* w3    = (const float*)d_in[7];
    const float* b3    = (const float*)d_in[8];
    float* out = (float*)d_out;

    char* ws = (char*)d_ws;
    short* w3cB  = (short*)(ws);                       // 72*2176*2      = 313,344
    short* w2cB  = (short*)(ws + 313344);              // 32*2048*2      = 131,072
    short* featT = (short*)(ws + 444416);              // 16*66*66*64*2  = 8,921,088
    short* F     = (short*)(ws + 9365504);             // 16*4096*264*2  = 34,603,008
    (void)ws_size; (void)in_sizes; (void)n_in; (void)out_size;

    prep_transpose_k<<<BB * HT, 256, 0, stream>>>(feat, w2, w3, b3, featT, w3cB, w2cB);
    conv_k<<<BB * 32, 512, 0, stream>>>(featT, w3cB, F);
    mlp_k<<<(BB * QQ) / 128, 256, 0, stream>>>(coord, cell, w1, b1, b2, w2cB, F, out);
}